// Round 9
// baseline (284.116 us; speedup 1.0000x reference)
//
#include <hip/hip_runtime.h>
#include <hip/hip_bf16.h>
#include <stdint.h>

#define BATCH 4
#define SEQ 2048
#define DIM 1024
#define HEADS 16
#define HD 64
#define BH (BATCH*HEADS)
#define NQKV (3*DIM)

typedef __attribute__((ext_vector_type(8))) short bf16x8;
typedef __attribute__((ext_vector_type(4))) short bf16x4;
typedef __attribute__((ext_vector_type(4))) float f32x4;
typedef __attribute__((ext_vector_type(16))) float f32x16;
typedef __attribute__((ext_vector_type(4))) unsigned u32x4;

#define MFMA16(a,b,c) __builtin_amdgcn_mfma_f32_16x16x32_bf16(a,b,c,0,0,0)
#define MFMA32(a,b,c) __builtin_amdgcn_mfma_f32_32x32x16_bf16(a,b,c,0,0,0)

__device__ inline short f2bf(float f){
    __hip_bfloat16 h = __float2bfloat16(f);
    return *reinterpret_cast<short*>(&h);
}
__device__ inline float bf2f(short s){
    unsigned u = ((unsigned)(unsigned short)s) << 16;
    float f;
    __builtin_memcpy(&f, &u, 4);
    return f;
}

// ---------------- convert x -> bf16 ----------------
__global__ void conv_bf16(const float* __restrict__ in, short* __restrict__ out, int n){
    int i = blockIdx.x*blockDim.x + threadIdx.x;
    if (i < n) out[i] = f2bf(in[i]);
}

// ---------------- transpose + convert (R x C f32) -> (C x R bf16) ----------------
__global__ void transpose_conv(const float* __restrict__ in, short* __restrict__ out, int R, int C){
    __shared__ float tile[32][33];
    int c0 = blockIdx.x*32, r0 = blockIdx.y*32;
    int tx = threadIdx.x, ty = threadIdx.y;   // block (32,8)
    #pragma unroll
    for (int dy = 0; dy < 32; dy += 8)
        tile[ty+dy][tx] = in[(size_t)(r0+ty+dy)*C + c0+tx];
    __syncthreads();
    #pragma unroll
    for (int dy = 0; dy < 32; dy += 8)
        out[(size_t)(c0+ty+dy)*R + r0+tx] = f2bf(tile[tx][ty+dy]);
}

// ---------------- m97-style GEMM: C[MxN] = A[MxK] * Bt[NxK]^T ----------------
template<int WRITE_BF16>
__global__ void gemm_bt(const short* __restrict__ A, const short* __restrict__ Bt,
                        void* __restrict__ Cout, int M, int N, int K)
{
    __shared__ short As[128*32];
    __shared__ short Bs[128*32];
    const int t = threadIdx.x;
    const int lane = t & 63, wave = t >> 6;
    const int wr = wave >> 1, wc = wave & 1;      // 2x2 waves, each 64x64
    const int nbn = N >> 7;
    const int bm = blockIdx.x / nbn, bn = blockIdx.x % nbn;
    const int m0 = bm*128, n0 = bn*128;
    const int l15 = lane & 15, lhi = lane >> 4;

    f32x4 acc[4][4];
    #pragma unroll
    for (int i=0;i<4;i++)
        #pragma unroll
        for (int j=0;j<4;j++) acc[i][j] = (f32x4){0.f,0.f,0.f,0.f};

    for (int k0 = 0; k0 < K; k0 += 32) {
        #pragma unroll
        for (int it = 0; it < 2; ++it) {
            int base = (it*256 + wave*64)*8;      // wave-uniform elem offset into LDS tile
            int off  = base + lane*8;
            int row = off >> 5, col = off & 31;
            __builtin_amdgcn_global_load_lds(
                (const __attribute__((address_space(1))) void*)(A + (size_t)(m0+row)*K + k0 + col),
                (__attribute__((address_space(3))) void*)(As + base), 16, 0, 0);
            __builtin_amdgcn_global_load_lds(
                (const __attribute__((address_space(1))) void*)(Bt + (size_t)(n0+row)*K + k0 + col),
                (__attribute__((address_space(3))) void*)(Bs + base), 16, 0, 0);
        }
        __syncthreads();
        bf16x8 a[4], b[4];
        #pragma unroll
        for (int i=0;i<4;i++)
            a[i] = *(const bf16x8*)&As[(wr*64 + i*16 + l15)*32 + lhi*8];
        #pragma unroll
        for (int j=0;j<4;j++)
            b[j] = *(const bf16x8*)&Bs[(wc*64 + j*16 + l15)*32 + lhi*8];
        #pragma unroll
        for (int i=0;i<4;i++)
            #pragma unroll
            for (int j=0;j<4;j++)
                acc[i][j] = MFMA16(a[i], b[j], acc[i][j]);
        __syncthreads();
    }

    #pragma unroll
    for (int i=0;i<4;i++)
        #pragma unroll
        for (int j=0;j<4;j++)
            #pragma unroll
            for (int jj=0;jj<4;jj++) {
                int row = m0 + wr*64 + i*16 + lhi*4 + jj;
                int col = n0 + wc*64 + j*16 + l15;
                if (WRITE_BF16)
                    ((short*)Cout)[(size_t)row*N + col] = f2bf(acc[i][j][jj]);
                else
                    ((float*)Cout)[(size_t)row*N + col] = acc[i][j][jj];
            }
}

// ---------------- RoPE + scatter (all stores coalesced; V transposed via LDS) ----------------
__global__ __launch_bounds__(256) void rope_scatter(const short* __restrict__ qkvb,
                             short* __restrict__ qb, short* __restrict__ kb,
                             short* __restrict__ vtb,
                             float* __restrict__ kout, float* __restrict__ vout)
{
    __shared__ short vt[64*72];
    const int t = threadIdx.x;
    const int bh = blockIdx.x >> 5;
    const int sb = blockIdx.x & 31;
    const int b = bh >> 4, h = bh & 15;
    const int s_loc = t >> 2, ic = (t & 3) << 3;
    const int s = (sb << 6) + s_loc;
    const size_t rowbase = ((size_t)(b*SEQ + s))*NQKV + h*HD;

    bf16x8 q1 = *(const bf16x8*)&qkvb[rowbase + ic];
    bf16x8 q2 = *(const bf16x8*)&qkvb[rowbase + ic + 32];
    bf16x8 k1 = *(const bf16x8*)&qkvb[rowbase + DIM + ic];
    bf16x8 k2 = *(const bf16x8*)&qkvb[rowbase + DIM + ic + 32];
    bf16x8 v1 = *(const bf16x8*)&qkvb[rowbase + 2*DIM + ic];
    bf16x8 v2 = *(const bf16x8*)&qkvb[rowbase + 2*DIM + ic + 32];

    const float QS = 0.125f * 1.4426950408889634f;
    bf16x8 qo1, qo2, ko1, ko2;
    float k1f[8], k2f[8], v1f[8], v2f[8];
    #pragma unroll
    for (int j=0;j<8;j++){
        int i = ic + j;
        float inv = exp2f(-(float)i * (13.287712379549449f/32.0f));
        float ang = (float)s * inv;
        float sn, cs;
        sincosf(ang, &sn, &cs);
        float q1f = bf2f(q1[j]), q2f = bf2f(q2[j]);
        float ka = bf2f(k1[j]), kb_ = bf2f(k2[j]);
        float qr1 = q1f*cs - q2f*sn, qr2 = q2f*cs + q1f*sn;
        float kr1 = ka*cs - kb_*sn,  kr2 = kb_*cs + ka*sn;
        qo1[j] = f2bf(qr1*QS); qo2[j] = f2bf(qr2*QS);
        ko1[j] = f2bf(kr1);    ko2[j] = f2bf(kr2);
        k1f[j] = kr1; k2f[j] = kr2;
        v1f[j] = bf2f(v1[j]); v2f[j] = bf2f(v2[j]);
    }

    const size_t obase = ((size_t)bh*SEQ + s)*HD;
    *(bf16x8*)&qb[obase+ic]      = qo1;
    *(bf16x8*)&qb[obase+ic+32]   = qo2;
    *(bf16x8*)&kb[obase+ic]      = ko1;
    *(bf16x8*)&kb[obase+ic+32]   = ko2;
    #pragma unroll
    for (int j4=0;j4<2;j4++){
        *(f32x4*)&kout[obase+ic+j4*4]    = (f32x4){k1f[j4*4],k1f[j4*4+1],k1f[j4*4+2],k1f[j4*4+3]};
        *(f32x4*)&kout[obase+ic+32+j4*4] = (f32x4){k2f[j4*4],k2f[j4*4+1],k2f[j4*4+2],k2f[j4*4+3]};
        *(f32x4*)&vout[obase+ic+j4*4]    = (f32x4){v1f[j4*4],v1f[j4*4+1],v1f[j4*4+2],v1f[j4*4+3]};
        *(f32x4*)&vout[obase+ic+32+j4*4] = (f32x4){v2f[j4*4],v2f[j4*4+1],v2f[j4*4+2],v2f[j4*4+3]};
    }

    // stage V transposed: row i (0..63), 8 chunks of 8 s-elems, chunk-swizzled
    #pragma unroll
    for (int j=0;j<8;j++){
        int i = ic + j;
        vt[i*72 + ((((s_loc>>3) ^ (i&7) ^ (i>>3)) & 7)<<3) + (s_loc&7)] = v1[j];
        int i2 = i + 32;
        vt[i2*72 + ((((s_loc>>3) ^ (i2&7) ^ (i2>>3)) & 7)<<3) + (s_loc&7)] = v2[j];
    }
    __syncthreads();

    // phase 2: coalesced vtb store. i_out = t>>2, g = t&3 -> s chunk 2g, 2g+1
    const int i_out = t >> 2, g = t & 3;
    int c0 = 2*g, c1 = 2*g+1;
    bf16x8 r0 = *(const bf16x8*)&vt[i_out*72 + ((((c0) ^ (i_out&7) ^ (i_out>>3)) & 7)<<3)];
    bf16x8 r1 = *(const bf16x8*)&vt[i_out*72 + ((((c1) ^ (i_out&7) ^ (i_out>>3)) & 7)<<3)];
    size_t vrow = ((size_t)bh*HD + i_out)*SEQ + (sb<<6) + g*16;
    *(bf16x8*)&vtb[vrow]     = r0;
    *(bf16x8*)&vtb[vrow + 8] = r1;
}

// ---------------- flash attention, partial (KV-split across blocks, 32x32 MFMA) ----------------
// 1 wave/block, 32-row q-tile, no-max softmax (q pre-scaled by 0.125*log2e).
// S^T = K.Q^T via mfma_32x32x16: col=q=lane&31, row=kv=(reg&3)+8(reg>>2)+4(lane>>5).
// P redistribution to PV A-frag done IN-REGISTER: 8 bf16-pair packs + 8 shfl_xor(32)
// + static-indexed selects. No LDS, no lgkmcnt stalls.
__global__ __launch_bounds__(64) void attn_partial(
        const short* __restrict__ qb, const short* __restrict__ kb,
        const short* __restrict__ vtb, short* __restrict__ obuf,
        float* __restrict__ lbuf)
{
    const int lane = threadIdx.x;
    const int wg = blockIdx.x;               // 4096 = 8x * 8bh-hi * 32pp * 2half
    const int x = wg & 7;                    // XCD swizzle
    const int r = wg >> 3;                   // 0..511
    const int half = r & 1;
    const int pp = (r >> 1) & 31;
    const int bh = (x << 3) | (r >> 6);
    const int l31 = lane & 31;
    const int H = lane >> 5;                 // 0 or 1
    const size_t sbase = (size_t)bh * SEQ * HD;
    const short* vbase = vtb + (size_t)bh * HD * SEQ;

    #pragma unroll 1
    for (int part = 0; part < 2; ++part) {
        const int qt = part ? (63 - pp) : pp;
        const int q0 = qt << 5;
        const int n  = qt + 1;               // total kv32 steps for this tile
        const int mid = (n + 1) >> 1;
        const int lo = half ? mid : 0;
        const int hi = half ? n : mid;

        // Q frag: Q[q0+l31][hd=16i+H*8 .. +7], i=0..3
        bf16x8 qf[4];
        #pragma unroll
        for (int i=0;i<4;i++)
            qf[i] = *(const bf16x8*)&qb[sbase + (size_t)(q0 + l31)*HD + i*16 + H*8];

        f32x16 o[2];
        #pragma unroll
        for (int nn=0;nn<2;nn++)
            #pragma unroll
            for (int rr=0;rr<16;rr++) o[nn][rr] = 0.f;
        float lsum = 0.f;

        // prefetch K for first step
        bf16x8 kf[4];
        #pragma unroll
        for (int i=0;i<4;i++)
            kf[i] = *(const bf16x8*)&kb[sbase + (size_t)(lo*32 + l31)*HD + i*16 + H*8];

        #pragma unroll 1
        for (int step = lo; step < hi; ++step) {
            const int kv0 = step << 5;

            bf16x8 kn[4];
            if (step + 1 < hi) {
                #pragma unroll
                for (int i=0;i<4;i++)
                    kn[i] = *(const bf16x8*)&kb[sbase + (size_t)(kv0+32 + l31)*HD + i*16 + H*8];
            }
            // V frags: B[kv][d]: lane holds V[kv0+16m+H*8+j][d=32nn+l31]
            bf16x8 vf[2][2];
            #pragma unroll
            for (int nn=0;nn<2;nn++)
                #pragma unroll
                for (int m=0;m<2;m++)
                    vf[nn][m] = *(const bf16x8*)&vbase[(size_t)(nn*32 + l31)*SEQ + kv0 + m*16 + H*8];

            // S^T[kv][q]: A=K rows, B=Q rows
            __builtin_amdgcn_s_setprio(1);
            f32x16 sacc;
            #pragma unroll
            for (int rr=0;rr<16;rr++) sacc[rr] = 0.f;
            #pragma unroll
            for (int i=0;i<4;i++)
                sacc = MFMA32(kf[i], qf[i], sacc);
            __builtin_amdgcn_s_setprio(0);

            if (step == n-1) {   // diagonal tile: mask kv > q
                #pragma unroll
                for (int rr=0;rr<16;rr++){
                    int kv = kv0 + (rr&3) + 8*(rr>>2) + 4*H;
                    int q  = q0 + l31;
                    if (kv > q) sacc[rr] = -3.0e38f;
                }
            }

            // P = exp2(s); private partial row-sum (q = l31)
            float p[16];
            #pragma unroll
            for (int rr=0;rr<16;rr++){
                p[rr] = exp2f(sacc[rr]);
                lsum += p[rr];
            }

            // pack pairs: W[j] = bf16(p[2j]) | bf16(p[2j+1])<<16
            unsigned W[8], Pp[8];
            #pragma unroll
            for (int j=0;j<8;j++)
                W[j] = (unsigned)(unsigned short)f2bf(p[2*j])
                     | ((unsigned)(unsigned short)f2bf(p[2*j+1]) << 16);
            #pragma unroll
            for (int j=0;j<8;j++)
                Pp[j] = __shfl_xor(W[j], 32);

            // assemble PV A-frags: pa[m] = P[q=l31][kv=16m + H*8 + 0..7]
            u32x4 paw[2];
            #pragma unroll
            for (int m=0;m<2;m++)
                #pragma unroll
                for (int w=0;w<4;w++){
                    int j0 = (w&1) + 4*m;
                    unsigned c0 = (w<2) ? W[j0]    : Pp[j0];      // if H==0
                    unsigned c1 = (w<2) ? Pp[j0+2] : W[j0+2];     // if H==1
                    paw[m][w] = H ? c1 : c0;
                }
            bf16x8 pa[2];
            __builtin_memcpy(&pa[0], &paw[0], 16);
            __builtin_memcpy(&pa[1], &paw[1], 16);

            // PV: O[q][d] += P.V
            __builtin_amdgcn_s_setprio(1);
            #pragma unroll
            for (int nn=0;nn<2;nn++)
                #pragma unroll
                for (int m=0;m<2;m++)
                    o[nn] = MFMA32(pa[m], vf[nn][m], o[nn]);
            __builtin_amdgcn_s_setprio(0);

            if (step + 1 < hi) {
                #pragma unroll
                for (int i=0;i<4;i++) kf[i] = kn[i];
            }
        }

        // write unnormalized partial O (bf16) + partial row-sums (f32)
        short* ob = obuf + (size_t)(((bh << 6) | qt)*2 + half) * 2048;
        #pragma unroll
        for (int nn=0;nn<2;nn++)
            #pragma unroll
            for (int rr=0;rr<16;rr++){
                int qloc = (rr&3) + 8*(rr>>2) + 4*H;
                ob[qloc*64 + nn*32 + l31] = f2bf(o[nn][rr]);
            }
        lsum += __shfl_xor(lsum, 32);
        float* lb = lbuf + (size_t)(((bh << 6) | qt)*2 + half) * 32;
        if (lane < 32) lb[l31] = lsum;
    }
}

// ---------------- combine partials -> aob (bf16) ----------------
// grid 4096 = BH(64) * 64 q-tiles
__global__ __launch_bounds__(256) void attn_combine(const short* __restrict__ obuf,
                                                    const float* __restrict__ lbuf,
                                                    short* __restrict__ aob)
{
    const int t = threadIdx.x;
    const int tile = blockIdx.x;        // bh*64 + qt
    const int bh = tile >> 6, qt = tile & 63;
    const int b = bh >> 4, h = bh & 15;
    const int q0 = qt << 5;
    const short* o0 = obuf + (size_t)(tile*2) * 2048;
    const short* o1 = o0 + 2048;
    const float* lb = lbuf + (size_t)(tile*2) * 32;
    const int row = t >> 3, c0 = (t & 7) << 3;

    float inv = 1.0f / (lb[row] + lb[32 + row]);
    bf16x8 a = *(const bf16x8*)&o0[row*64 + c0];
    bf16x8 bq = *(const bf16x8*)&o1[row*64 + c0];
    bf16x8 ov;
    #pragma unroll
    for (int j=0;j<8;j++)
        ov[j] = f2bf((bf2f(a[j]) + bf2f(bq[j])) * inv);
    *(bf16x8*)&aob[((size_t)(b*SEQ + q0 + row))*DIM + h*HD + c0] = ov;
}

extern "C" void kernel_launch(void* const* d_in, const int* in_sizes, int n_in,
                              void* d_out, int out_size, void* d_ws, size_t ws_size,
                              hipStream_t stream) {
    const float* x     = (const float*)d_in[0];
    const float* w_qkv = (const float*)d_in[1];
    const float* w_out = (const float*)d_in[2];
    float* out  = (float*)d_out;
    float* kout = out + (size_t)BATCH*SEQ*DIM;          // 8388608
    float* vout = kout + (size_t)BH*SEQ*HD;             // +8388608

    char* ws = (char*)d_ws;
    short* xb    = (short*)(ws + 0);                    // 16 MB
    short* wqkvT = (short*)(ws + 16777216);             // 6 MB
    short* woutT = (short*)(ws + 23068672);             // 2 MB
    short* qkvb  = (short*)(ws + 25165824);             // 48 MB (8192x3072 bf16)
    // obuf/lbuf reuse the qkvb region (dead after rope_scatter):
    //   obuf: 4096 tiles * 2 halves * 2048 bf16 = 33.55 MB
    //   lbuf: 4096 * 2 * 32 f32 = 1.05 MB       -> total 34.6 MB < 48 MB
    short* obuf  = (short*)(ws + 25165824);
    float* lbuf  = (float*)(ws + 25165824 + 33554432);
    short* qb    = (short*)(ws + 75497472);             // 16 MB
    short* kb    = (short*)(ws + 92274688);             // 16 MB
    short* vtb   = (short*)(ws + 109051904);            // 16 MB
    short* aob   = (short*)(ws + 125829120);            // 16 MB

    conv_bf16<<<(BATCH*SEQ*DIM)/256, 256, 0, stream>>>(x, xb, BATCH*SEQ*DIM);
    transpose_conv<<<dim3(NQKV/32, DIM/32), dim3(32,8), 0, stream>>>(w_qkv, wqkvT, DIM, NQKV);
    transpose_conv<<<dim3(DIM/32, DIM/32), dim3(32,8), 0, stream>>>(w_out, woutT, DIM, DIM);

    gemm_bt<1><<<(8192/128)*(NQKV/128), 256, 0, stream>>>(xb, wqkvT, qkvb, 8192, NQKV, DIM);

    rope_scatter<<<BH*(SEQ/64), 256, 0, stream>>>(qkvb, qb, kb, vtb, kout, vout);

    attn_partial<<<4096, 64, 0, stream>>>(qb, kb, vtb, obuf, lbuf);
    attn_combine<<<4096, 256, 0, stream>>>(obuf, lbuf, aob);

    gemm_bt<0><<<(8192/128)*(DIM/128), 256, 0, stream>>>(aob, woutT, out, 8192, DIM, DIM);
}

// Round 10
// 237.368 us; speedup vs baseline: 1.1969x; 1.1969x over previous
//
#include <hip/hip_runtime.h>
#include <hip/hip_bf16.h>
#include <stdint.h>

#define BATCH 4
#define SEQ 2048
#define DIM 1024
#define HEADS 16
#define HD 64
#define BH (BATCH*HEADS)
#define NQKV (3*DIM)

typedef __attribute__((ext_vector_type(8))) short bf16x8;
typedef __attribute__((ext_vector_type(4))) short bf16x4;
typedef __attribute__((ext_vector_type(4))) float f32x4;
typedef __attribute__((ext_vector_type(16))) float f32x16;
typedef __attribute__((ext_vector_type(4))) unsigned u32x4;

#define MFMA16(a,b,c) __builtin_amdgcn_mfma_f32_16x16x32_bf16(a,b,c,0,0,0)
#define MFMA32(a,b,c) __builtin_amdgcn_mfma_f32_32x32x16_bf16(a,b,c,0,0,0)

__device__ inline short f2bf(float f){
    __hip_bfloat16 h = __float2bfloat16(f);
    return *reinterpret_cast<short*>(&h);
}
__device__ inline float bf2f(short s){
    unsigned u = ((unsigned)(unsigned short)s) << 16;
    float f;
    __builtin_memcpy(&f, &u, 4);
    return f;
}

// ---------------- convert x -> bf16 ----------------
__global__ void conv_bf16(const float* __restrict__ in, short* __restrict__ out, int n){
    int i = blockIdx.x*blockDim.x + threadIdx.x;
    if (i < n) out[i] = f2bf(in[i]);
}

// ---------------- transpose + convert (R x C f32) -> (C x R bf16) ----------------
__global__ void transpose_conv(const float* __restrict__ in, short* __restrict__ out, int R, int C){
    __shared__ float tile[32][33];
    int c0 = blockIdx.x*32, r0 = blockIdx.y*32;
    int tx = threadIdx.x, ty = threadIdx.y;   // block (32,8)
    #pragma unroll
    for (int dy = 0; dy < 32; dy += 8)
        tile[ty+dy][tx] = in[(size_t)(r0+ty+dy)*C + c0+tx];
    __syncthreads();
    #pragma unroll
    for (int dy = 0; dy < 32; dy += 8)
        out[(size_t)(c0+ty+dy)*R + r0+tx] = f2bf(tile[tx][ty+dy]);
}

// ---------------- m97-style GEMM: C[MxN] = A[MxK] * Bt[NxK]^T ----------------
template<int WRITE_BF16>
__global__ void gemm_bt(const short* __restrict__ A, const short* __restrict__ Bt,
                        void* __restrict__ Cout, int M, int N, int K)
{
    __shared__ short As[128*32];
    __shared__ short Bs[128*32];
    const int t = threadIdx.x;
    const int lane = t & 63, wave = t >> 6;
    const int wr = wave >> 1, wc = wave & 1;      // 2x2 waves, each 64x64
    const int nbn = N >> 7;
    const int bm = blockIdx.x / nbn, bn = blockIdx.x % nbn;
    const int m0 = bm*128, n0 = bn*128;
    const int l15 = lane & 15, lhi = lane >> 4;

    f32x4 acc[4][4];
    #pragma unroll
    for (int i=0;i<4;i++)
        #pragma unroll
        for (int j=0;j<4;j++) acc[i][j] = (f32x4){0.f,0.f,0.f,0.f};

    for (int k0 = 0; k0 < K; k0 += 32) {
        #pragma unroll
        for (int it = 0; it < 2; ++it) {
            int base = (it*256 + wave*64)*8;      // wave-uniform elem offset into LDS tile
            int off  = base + lane*8;
            int row = off >> 5, col = off & 31;
            __builtin_amdgcn_global_load_lds(
                (const __attribute__((address_space(1))) void*)(A + (size_t)(m0+row)*K + k0 + col),
                (__attribute__((address_space(3))) void*)(As + base), 16, 0, 0);
            __builtin_amdgcn_global_load_lds(
                (const __attribute__((address_space(1))) void*)(Bt + (size_t)(n0+row)*K + k0 + col),
                (__attribute__((address_space(3))) void*)(Bs + base), 16, 0, 0);
        }
        __syncthreads();
        bf16x8 a[4], b[4];
        #pragma unroll
        for (int i=0;i<4;i++)
            a[i] = *(const bf16x8*)&As[(wr*64 + i*16 + l15)*32 + lhi*8];
        #pragma unroll
        for (int j=0;j<4;j++)
            b[j] = *(const bf16x8*)&Bs[(wc*64 + j*16 + l15)*32 + lhi*8];
        #pragma unroll
        for (int i=0;i<4;i++)
            #pragma unroll
            for (int j=0;j<4;j++)
                acc[i][j] = MFMA16(a[i], b[j], acc[i][j]);
        __syncthreads();
    }

    #pragma unroll
    for (int i=0;i<4;i++)
        #pragma unroll
        for (int j=0;j<4;j++)
            #pragma unroll
            for (int jj=0;jj<4;jj++) {
                int row = m0 + wr*64 + i*16 + lhi*4 + jj;
                int col = n0 + wc*64 + j*16 + l15;
                if (WRITE_BF16)
                    ((short*)Cout)[(size_t)row*N + col] = f2bf(acc[i][j][jj]);
                else
                    ((float*)Cout)[(size_t)row*N + col] = acc[i][j][jj];
            }
}

// ---------------- RoPE + scatter into MFMA-fragment-packed layouts ----------------
// qp/kp: [bh][tile(32 rows)][i=0..3][lane=0..63][j=0..7] bf16,
//        element = X[kv0+(lane&31)][16i + (lane>>5)*8 + j]   (q pre-scaled)
// vp:    [bh][tile][nn=0..1][m=0..1][lane][j] bf16,
//        element = V[kv0 + 16m + (lane>>5)*8 + j][32nn + (lane&31)]
// kout/vout: (BH,S,HD) f32 outputs (row-major, unchanged)
__global__ __launch_bounds__(256) void rope_scatter(const short* __restrict__ qkvb,
                             short* __restrict__ qp, short* __restrict__ kp,
                             short* __restrict__ vp,
                             float* __restrict__ kout, float* __restrict__ vout)
{
    __shared__ short vt[64*72];
    const int t = threadIdx.x;
    const int bh = blockIdx.x >> 5;
    const int sb = blockIdx.x & 31;
    const int b = bh >> 4, h = bh & 15;
    const int s_loc = t >> 2, ic = (t & 3) << 3;
    const int s = (sb << 6) + s_loc;
    const size_t rowbase = ((size_t)(b*SEQ + s))*NQKV + h*HD;

    bf16x8 q1 = *(const bf16x8*)&qkvb[rowbase + ic];
    bf16x8 q2 = *(const bf16x8*)&qkvb[rowbase + ic + 32];
    bf16x8 k1 = *(const bf16x8*)&qkvb[rowbase + DIM + ic];
    bf16x8 k2 = *(const bf16x8*)&qkvb[rowbase + DIM + ic + 32];
    bf16x8 v1 = *(const bf16x8*)&qkvb[rowbase + 2*DIM + ic];
    bf16x8 v2 = *(const bf16x8*)&qkvb[rowbase + 2*DIM + ic + 32];

    const float QS = 0.125f * 1.4426950408889634f;
    bf16x8 qo1, qo2, ko1, ko2;
    float k1f[8], k2f[8], v1f[8], v2f[8];
    #pragma unroll
    for (int j=0;j<8;j++){
        int i = ic + j;
        float inv = exp2f(-(float)i * (13.287712379549449f/32.0f));
        float ang = (float)s * inv;
        float sn, cs;
        sincosf(ang, &sn, &cs);
        float q1f = bf2f(q1[j]), q2f = bf2f(q2[j]);
        float ka = bf2f(k1[j]), kb_ = bf2f(k2[j]);
        float qr1 = q1f*cs - q2f*sn, qr2 = q2f*cs + q1f*sn;
        float kr1 = ka*cs - kb_*sn,  kr2 = kb_*cs + ka*sn;
        qo1[j] = f2bf(qr1*QS); qo2[j] = f2bf(qr2*QS);
        ko1[j] = f2bf(kr1);    ko2[j] = f2bf(kr2);
        k1f[j] = kr1; k2f[j] = kr2;
        v1f[j] = bf2f(v1[j]); v2f[j] = bf2f(v2[j]);
    }

    // f32 K/V outputs (row-major, coalesced)
    const size_t obase = ((size_t)bh*SEQ + s)*HD;
    #pragma unroll
    for (int j4=0;j4<2;j4++){
        *(f32x4*)&kout[obase+ic+j4*4]    = (f32x4){k1f[j4*4],k1f[j4*4+1],k1f[j4*4+2],k1f[j4*4+3]};
        *(f32x4*)&kout[obase+ic+32+j4*4] = (f32x4){k2f[j4*4],k2f[j4*4+1],k2f[j4*4+2],k2f[j4*4+3]};
        *(f32x4*)&vout[obase+ic+j4*4]    = (f32x4){v1f[j4*4],v1f[j4*4+1],v1f[j4*4+2],v1f[j4*4+3]};
        *(f32x4*)&vout[obase+ic+32+j4*4] = (f32x4){v2f[j4*4],v2f[j4*4+1],v2f[j4*4+2],v2f[j4*4+3]};
    }

    // packed Q/K stores: col group [ic,ic+8) -> g1 = ic>>3, [32+ic,..) -> g2 = 4+(ic>>3)
    {
        const int tkv = (sb << 1) + (s_loc >> 5);
        const int rlo = s_loc & 31;
        const int g1 = ic >> 3,   i1 = g1 >> 1, H1 = g1 & 1;
        const int g2 = 4+(ic>>3), i2 = g2 >> 1, H2 = g2 & 1;
        const size_t tb = ((size_t)bh*64 + tkv)*4;
        *(bf16x8*)&qp[(tb + i1)*512 + (H1*32 + rlo)*8] = qo1;
        *(bf16x8*)&qp[(tb + i2)*512 + (H2*32 + rlo)*8] = qo2;
        *(bf16x8*)&kp[(tb + i1)*512 + (H1*32 + rlo)*8] = ko1;
        *(bf16x8*)&kp[(tb + i2)*512 + (H2*32 + rlo)*8] = ko2;
    }

    // stage V transposed: row i (0..63), 8 chunks of 8 s-elems, chunk-swizzled
    #pragma unroll
    for (int j=0;j<8;j++){
        int i = ic + j;
        vt[i*72 + ((((s_loc>>3) ^ (i&7) ^ (i>>3)) & 7)<<3) + (s_loc&7)] = v1[j];
        int i2 = i + 32;
        vt[i2*72 + ((((s_loc>>3) ^ (i2&7) ^ (i2>>3)) & 7)<<3) + (s_loc&7)] = v2[j];
    }
    __syncthreads();

    // phase 2: packed vp store. thread (i_out = hd, g) handles s-chunks 2g, 2g+1
    const int i_out = t >> 2, g = t & 3;
    const int nn = i_out >> 5, l31v = i_out & 31;
    #pragma unroll
    for (int cc=0; cc<2; ++cc){
        int c = 2*g + cc;                     // s-chunk 0..7 within the 64-row block
        bf16x8 rv = *(const bf16x8*)&vt[i_out*72 + ((((c) ^ (i_out&7) ^ (i_out>>3)) & 7)<<3)];
        int tkv = (sb << 1) + (c >> 2);
        int m = (c >> 1) & 1, H = c & 1;
        size_t va = ((((size_t)bh*64 + tkv)*2 + nn)*2 + m)*512 + (H*32 + l31v)*8;
        *(bf16x8*)&vp[va] = rv;
    }
}

// ---------------- flash attention, partial (KV-split across blocks, 32x32 MFMA) ----------------
// All Q/K/V loads are fully-coalesced 1KB wave-loads from fragment-packed buffers.
__global__ __launch_bounds__(64) void attn_partial(
        const short* __restrict__ qp, const short* __restrict__ kp,
        const short* __restrict__ vp, short* __restrict__ obuf,
        float* __restrict__ lbuf)
{
    const int lane = threadIdx.x;
    const int wg = blockIdx.x;               // 4096 = 8x * 8bh-hi * 32pp * 2half
    const int x = wg & 7;                    // XCD swizzle
    const int r = wg >> 3;                   // 0..511
    const int half = r & 1;
    const int pp = (r >> 1) & 31;
    const int bh = (x << 3) | (r >> 6);
    const int l31 = lane & 31;
    const int H = lane >> 5;                 // 0 or 1
    const short* kbase = kp + (size_t)bh * 64 * 2048;
    const short* vbase = vp + (size_t)bh * 64 * 2048;
    const short* qbase = qp + (size_t)bh * 64 * 2048;

    #pragma unroll 1
    for (int part = 0; part < 2; ++part) {
        const int qt = part ? (63 - pp) : pp;
        const int q0 = qt << 5;
        const int n  = qt + 1;               // total kv32 steps for this tile
        const int mid = (n + 1) >> 1;
        const int lo = half ? mid : 0;
        const int hi = half ? n : mid;

        // Q frag (packed, coalesced)
        bf16x8 qf[4];
        #pragma unroll
        for (int i=0;i<4;i++)
            qf[i] = *(const bf16x8*)&qbase[((size_t)qt*4 + i)*512 + lane*8];

        f32x16 o[2];
        #pragma unroll
        for (int nn=0;nn<2;nn++)
            #pragma unroll
            for (int rr=0;rr<16;rr++) o[nn][rr] = 0.f;
        float lsum = 0.f;

        // prefetch K for first step (packed, coalesced)
        bf16x8 kf[4];
        #pragma unroll
        for (int i=0;i<4;i++)
            kf[i] = *(const bf16x8*)&kbase[((size_t)lo*4 + i)*512 + lane*8];

        #pragma unroll 1
        for (int step = lo; step < hi; ++step) {
            const int kv0 = step << 5;

            bf16x8 kn[4];
            if (step + 1 < hi) {
                #pragma unroll
                for (int i=0;i<4;i++)
                    kn[i] = *(const bf16x8*)&kbase[((size_t)(step+1)*4 + i)*512 + lane*8];
            }
            // V frags (packed, coalesced)
            bf16x8 vf[2][2];
            #pragma unroll
            for (int nn=0;nn<2;nn++)
                #pragma unroll
                for (int m=0;m<2;m++)
                    vf[nn][m] = *(const bf16x8*)&vbase[((size_t)step*4 + nn*2 + m)*512 + lane*8];

            // S^T[kv][q]: A=K rows, B=Q rows
            __builtin_amdgcn_s_setprio(1);
            f32x16 sacc;
            #pragma unroll
            for (int rr=0;rr<16;rr++) sacc[rr] = 0.f;
            #pragma unroll
            for (int i=0;i<4;i++)
                sacc = MFMA32(kf[i], qf[i], sacc);
            __builtin_amdgcn_s_setprio(0);

            if (step == n-1) {   // diagonal tile: mask kv > q
                #pragma unroll
                for (int rr=0;rr<16;rr++){
                    int kv = kv0 + (rr&3) + 8*(rr>>2) + 4*H;
                    int q  = q0 + l31;
                    if (kv > q) sacc[rr] = -3.0e38f;
                }
            }

            // P = exp2(s); private partial row-sum (q = l31)
            float p[16];
            #pragma unroll
            for (int rr=0;rr<16;rr++){
                p[rr] = exp2f(sacc[rr]);
                lsum += p[rr];
            }

            // pack pairs: W[j] = bf16(p[2j]) | bf16(p[2j+1])<<16
            unsigned W[8], Pp[8];
            #pragma unroll
            for (int j=0;j<8;j++)
                W[j] = (unsigned)(unsigned short)f2bf(p[2*j])
                     | ((unsigned)(unsigned short)f2bf(p[2*j+1]) << 16);
            #pragma unroll
            for (int j=0;j<8;j++)
                Pp[j] = __shfl_xor(W[j], 32);

            // assemble PV A-frags: pa[m] = P[q=l31][kv=16m + H*8 + 0..7]
            u32x4 paw[2];
            #pragma unroll
            for (int m=0;m<2;m++)
                #pragma unroll
                for (int w=0;w<4;w++){
                    int j0 = (w&1) + 4*m;
                    unsigned c0 = (w<2) ? W[j0]    : Pp[j0];      // if H==0
                    unsigned c1 = (w<2) ? Pp[j0+2] : W[j0+2];     // if H==1
                    paw[m][w] = H ? c1 : c0;
                }
            bf16x8 pa[2];
            __builtin_memcpy(&pa[0], &paw[0], 16);
            __builtin_memcpy(&pa[1], &paw[1], 16);

            // PV: O[q][d] += P.V
            __builtin_amdgcn_s_setprio(1);
            #pragma unroll
            for (int nn=0;nn<2;nn++)
                #pragma unroll
                for (int m=0;m<2;m++)
                    o[nn] = MFMA32(pa[m], vf[nn][m], o[nn]);
            __builtin_amdgcn_s_setprio(0);

            if (step + 1 < hi) {
                #pragma unroll
                for (int i=0;i<4;i++) kf[i] = kn[i];
            }
        }

        // write unnormalized partial O (bf16) + partial row-sums (f32)
        short* ob = obuf + (size_t)(((bh << 6) | qt)*2 + half) * 2048;
        #pragma unroll
        for (int nn=0;nn<2;nn++)
            #pragma unroll
            for (int rr=0;rr<16;rr++){
                int qloc = (rr&3) + 8*(rr>>2) + 4*H;
                ob[qloc*64 + nn*32 + l31] = f2bf(o[nn][rr]);
            }
        lsum += __shfl_xor(lsum, 32);
        float* lb = lbuf + (size_t)(((bh << 6) | qt)*2 + half) * 32;
        if (lane < 32) lb[l31] = lsum;
    }
}

// ---------------- combine partials -> aob (bf16) ----------------
// grid 4096 = BH(64) * 64 q-tiles
__global__ __launch_bounds__(256) void attn_combine(const short* __restrict__ obuf,
                                                    const float* __restrict__ lbuf,
                                                    short* __restrict__ aob)
{
    const int t = threadIdx.x;
    const int tile = blockIdx.x;        // bh*64 + qt
    const int bh = tile >> 6, qt = tile & 63;
    const int b = bh >> 4, h = bh & 15;
    const int q0 = qt << 5;
    const short* o0 = obuf + (size_t)(tile*2) * 2048;
    const short* o1 = o0 + 2048;
    const float* lb = lbuf + (size_t)(tile*2) * 32;
    const int row = t >> 3, c0 = (t & 7) << 3;

    float inv = 1.0f / (lb[row] + lb[32 + row]);
    bf16x8 a = *(const bf16x8*)&o0[row*64 + c0];
    bf16x8 bq = *(const bf16x8*)&o1[row*64 + c0];
    bf16x8 ov;
    #pragma unroll
    for (int j=0;j<8;j++)
        ov[j] = f2bf((bf2f(a[j]) + bf2f(bq[j])) * inv);
    *(bf16x8*)&aob[((size_t)(b*SEQ + q0 + row))*DIM + h*HD + c0] = ov;
}

extern "C" void kernel_launch(void* const* d_in, const int* in_sizes, int n_in,
                              void* d_out, int out_size, void* d_ws, size_t ws_size,
                              hipStream_t stream) {
    const float* x     = (const float*)d_in[0];
    const float* w_qkv = (const float*)d_in[1];
    const float* w_out = (const float*)d_in[2];
    float* out  = (float*)d_out;
    float* kout = out + (size_t)BATCH*SEQ*DIM;          // 8388608
    float* vout = kout + (size_t)BH*SEQ*HD;             // +8388608

    char* ws = (char*)d_ws;
    short* xb    = (short*)(ws + 0);                    // 16 MB
    short* wqkvT = (short*)(ws + 16777216);             // 6 MB
    short* woutT = (short*)(ws + 23068672);             // 2 MB
    short* qkvb  = (short*)(ws + 25165824);             // 48 MB (8192x3072 bf16)
    // obuf/lbuf reuse the qkvb region (dead after rope_scatter):
    //   obuf: 4096 tiles * 2 halves * 2048 bf16 = 33.55 MB
    //   lbuf: 4096 * 2 * 32 f32 = 1.05 MB       -> total 34.6 MB < 48 MB
    short* obuf  = (short*)(ws + 25165824);
    float* lbuf  = (float*)(ws + 25165824 + 33554432);
    short* qp    = (short*)(ws + 75497472);             // 16 MB (packed Q frags)
    short* kp    = (short*)(ws + 92274688);             // 16 MB (packed K frags)
    short* vp    = (short*)(ws + 109051904);            // 16 MB (packed V frags)
    short* aob   = (short*)(ws + 125829120);            // 16 MB

    conv_bf16<<<(BATCH*SEQ*DIM)/256, 256, 0, stream>>>(x, xb, BATCH*SEQ*DIM);
    transpose_conv<<<dim3(NQKV/32, DIM/32), dim3(32,8), 0, stream>>>(w_qkv, wqkvT, DIM, NQKV);
    transpose_conv<<<dim3(DIM/32, DIM/32), dim3(32,8), 0, stream>>>(w_out, woutT, DIM, DIM);

    gemm_bt<1><<<(8192/128)*(NQKV/128), 256, 0, stream>>>(xb, wqkvT, qkvb, 8192, NQKV, DIM);

    rope_scatter<<<BH*(SEQ/64), 256, 0, stream>>>(qkvb, qp, kp, vp, kout, vout);

    attn_partial<<<4096, 64, 0, stream>>>(qp, kp, vp, obuf, lbuf);
    attn_combine<<<4096, 256, 0, stream>>>(obuf, lbuf, aob);

    gemm_bt<0><<<(8192/128)*(DIM/128), 256, 0, stream>>>(aob, woutT, out, 8192, DIM, DIM);
}